// Round 5
// baseline (362.203 us; speedup 1.0000x reference)
//
#include <hip/hip_runtime.h>
#include <hip/hip_bf16.h>

#define HIDDEN 1024
#define B_SZ 32
#define S_SZ 2048
#define M_TOT (B_SZ * S_SZ)          // 65536 rows
#define MASKED_BIAS -10000.0f

using bf16   = __bf16;
using bf16x4 = __attribute__((ext_vector_type(4))) __bf16;
using bf16x8 = __attribute__((ext_vector_type(8))) __bf16;
using f32x4  = __attribute__((ext_vector_type(4))) float;

__device__ __forceinline__ float tanh_fast(float x) {
    float xc = fminf(fmaxf(x, -15.f), 15.f);
    float e2 = __expf(2.f * xc);
    return (e2 - 1.f) * __frcp_rn(e2 + 1.f);
}

// ---------------------------------------------------------------------------
// Kernel 0: W_K f32 -> bf16 row-major copy (B operand for the fused GEMM)
// ---------------------------------------------------------------------------
__global__ __launch_bounds__(256) void k_wconv(
    const float* __restrict__ W, bf16* __restrict__ out)
{
    int i = blockIdx.x * 256 + threadIdx.x;      // 131072 threads x 8 elems
    const float4* p = (const float4*)W + (size_t)i * 2;
    float4 a = p[0], b = p[1];
    bf16x8 v = { (bf16)a.x, (bf16)a.y, (bf16)a.z, (bf16)a.w,
                 (bf16)b.x, (bf16)b.y, (bf16)b.z, (bf16)b.w };
    *(bf16x8*)(out + (size_t)i * 8) = v;
}

// ---------------------------------------------------------------------------
// Kernel 1: hl_plus[b][g] = dot(h[b,:], W_h[g,:]) + b_h[g] + b_K[g] + b_cov[g]
// ---------------------------------------------------------------------------
__global__ __launch_bounds__(256) void k_hlplus(
    const float* __restrict__ h, const float* __restrict__ W_h,
    const float* __restrict__ b_h, const float* __restrict__ b_K,
    const float* __restrict__ b_cov, float* __restrict__ hl_plus)
{
    int wid  = blockIdx.x * 4 + (threadIdx.x >> 6);  // 0..32767
    int lane = threadIdx.x & 63;
    int b = wid & 31;
    int g = wid >> 5;
    const float4* hv = (const float4*)(h + b * HIDDEN);
    const float4* wv = (const float4*)(W_h + g * HIDDEN);
    float acc = 0.f;
#pragma unroll
    for (int i = 0; i < 4; ++i) {
        float4 a = hv[i * 64 + lane];
        float4 w = wv[i * 64 + lane];
        acc += a.x * w.x + a.y * w.y + a.z * w.z + a.w * w.w;
    }
#pragma unroll
    for (int off = 32; off; off >>= 1) acc += __shfl_xor(acc, off);
    if (lane == 0)
        hl_plus[b * HIDDEN + g] = acc + b_h[g] + b_K[g] + b_cov[g];
}

// ---------------------------------------------------------------------------
// Kernel 2: fused  e_part[nt][row] = sum_g tanh(K@W_K^T + hl_plus + cov*W_cov)
//                                     * W_v[g]
// 256x256 tile, BK=64, 8 waves (2Mx4N), 4 phases per K-tile, each:
//   {ds_read subtile | stage piece} -> bar -> lgkmcnt(0) ->
//   setprio(1) 16xMFMA setprio(0) -> [vmcnt(8) at phase 4] -> bar
// B via global_load_lds (bf16 prepass, pre-swizzled SOURCE, linear dest);
// A reg-staged f32->bf16, ds_write at slot = chunk ^ (row&7) (same involution).
// ---------------------------------------------------------------------------
#define NT_N 4          // 1024/256 n-tiles

__global__ __launch_bounds__(512) void k_fused(
    const float* __restrict__ Kin,      // [65536][1024] f32
    const bf16*  __restrict__ Bbf,      // [1024][1024] bf16 (W_K)
    const float* __restrict__ hl_plus,  // [32][1024]
    const float* __restrict__ W_cov,    // [1024]
    const float* __restrict__ cov,      // [65536]
    const float* __restrict__ W_v,      // [1024]
    float* __restrict__ e_part)         // [4][65536]
{
    __shared__ __align__(16) bf16 AsT[2][256][64];   // 64 KB total
    __shared__ __align__(16) bf16 BsT[2][256][64];   // 64 KB total
    __shared__ float e_buf[256][4];

    const int tid = threadIdx.x;
    // XCD-bijective swizzle: 1024 blocks, 128 per XCD; nt fastest within XCD.
    const int bid = blockIdx.x;
    const int lid = (bid & 7) * 128 + (bid >> 3);
    const int mt  = lid >> 2;            // 256 m-tiles
    const int nt  = lid & 3;             // 4 n-tiles
    const int row0 = mt * 256;
    const int col0 = nt * 256;

    const int w    = tid >> 6;           // wave 0..7
    const int lane = tid & 63;
    const int wr   = w >> 2;             // m-half 0..1
    const int wc   = w & 3;              // n-quarter 0..3
    const int lr   = lane & 15;
    const int kb   = lane >> 4;          // 0..3
    const int cswz = lr & 7;
    const int wrB  = wr * 128;
    const int wcB  = wc * 64;
    // logical 16B-chunk -> swizzled LDS col (bf16 elems), per k-slice
    const int colk0 = (kb ^ cswz) * 8;
    const int colk1 = ((4 + kb) ^ cswz) * 8;

    // ---- A staging geometry: thread -> row tid>>1, 128B half tid&1 ----
    const int arow  = tid >> 1;
    const int ahalf = tid & 1;
    const float4* Asrc =
        (const float4*)(Kin + (size_t)(row0 + arow) * HIDDEN + ahalf * 32);
    // ---- B gload: lane l -> LDS row (w*4+j)*8 + (l>>3), slot l&7;
    //      source chunk pre-swizzled so slot s holds chunk s ^ (row&7)
    const int brow_l = lane >> 3;                    // 0..7
    const int bcl    = (lane & 7) ^ brow_l;          // pre-swizzled chunk idx

    float4 aR[8];
    f32x4 acc[8][4] = {};

#define A_ISSUE(kt)                                                       \
    { const float4* p_ = Asrc + (kt) * 16;                                \
      _Pragma("unroll") for (int j = 0; j < 8; ++j) aR[j] = p_[j]; }

#define A_WRITE(BUF)                                                      \
    _Pragma("unroll") for (int j2 = 0; j2 < 4; ++j2) {                    \
        float4 u_ = aR[j2 * 2], v_ = aR[j2 * 2 + 1];                      \
        bf16x8 w8_ = { (bf16)u_.x, (bf16)u_.y, (bf16)u_.z, (bf16)u_.w,    \
                       (bf16)v_.x, (bf16)v_.y, (bf16)v_.z, (bf16)v_.w };  \
        int cl_ = (ahalf * 4 + j2) ^ (arow & 7);                          \
        *(bf16x8*)&AsT[BUF][arow][cl_ * 8] = w8_;                         \
    }

#define B_GLDS(kt, BUF)                                                   \
    _Pragma("unroll") for (int j = 0; j < 4; ++j) {                       \
        const bf16* gs_ = Bbf +                                           \
            (size_t)(col0 + (w * 4 + j) * 8 + brow_l) * HIDDEN +          \
            (kt) * 64 + bcl * 8;                                          \
        __builtin_amdgcn_global_load_lds(                                 \
            (const __attribute__((address_space(1))) void*)gs_,           \
            (__attribute__((address_space(3))) void*)&BsT[BUF][(w * 4 + j) * 8][0], \
            16, 0, 0);                                                    \
    }

#define RD_A(BUF, MP, COLK)                                               \
    _Pragma("unroll") for (int j = 0; j < 4; ++j)                         \
        afr[j] = *(const bf16x8*)&AsT[BUF][wrB + (MP) * 64 + j * 16 + lr][COLK];

#define RD_B(BUF, COLK)                                                   \
    _Pragma("unroll") for (int n = 0; n < 4; ++n)                         \
        bfr[n] = *(const bf16x8*)&BsT[BUF][wcB + n * 16 + lr][COLK];

#define MFMA16(MP)                                                        \
    __builtin_amdgcn_s_setprio(1);                                        \
    _Pragma("unroll") for (int j = 0; j < 4; ++j)                         \
        _Pragma("unroll") for (int n = 0; n < 4; ++n)                     \
            acc[(MP) * 4 + j][n] = __builtin_amdgcn_mfma_f32_16x16x32_bf16( \
                afr[j], bfr[n], acc[(MP) * 4 + j][n], 0, 0, 0);           \
    __builtin_amdgcn_s_setprio(0);

#define MEMBAR() asm volatile("" ::: "memory")
#define LGKM0()  asm volatile("s_waitcnt lgkmcnt(0)" ::: "memory")
#define VM(n)    asm volatile("s_waitcnt vmcnt(" #n ")" ::: "memory")
#define SBAR()   __builtin_amdgcn_s_barrier()
#define P_OPEN()  MEMBAR(); SBAR(); LGKM0();
#define P_CLOSE() MEMBAR(); SBAR();

    // ---- prologue: stage tile 0, issue A of tile 1 ----
    A_ISSUE(0)
    B_GLDS(0, 0)
    A_WRITE(0)                // compiler-counted vmcnt wait on aR (B0 in flight)
    A_ISSUE(1)
    VM(8);                    // drain B0 (A1 x8 remain in flight)
    LGKM0();                  // own A-writes drained before barrier
    MEMBAR(); SBAR();

    // ---- main loop: 2 tiles per iteration, tiles 0..13 ----
    for (int kt2 = 0; kt2 < 7; ++kt2) {
        const int t = kt2 * 2;
        {   // tile t (buf0): stage B(t+1)->buf1, A(t+1)->buf1, issue A(t+2)
            bf16x8 afr[4], bfr[4];
            RD_B(0, colk0) RD_A(0, 0, colk0) B_GLDS(t + 1, 1)
            P_OPEN() MFMA16(0) P_CLOSE()
            RD_A(0, 1, colk0) A_WRITE(1)
            P_OPEN() MFMA16(1) P_CLOSE()
            RD_B(0, colk1) RD_A(0, 0, colk1) A_ISSUE(t + 2)
            P_OPEN() MFMA16(0) P_CLOSE()
            RD_A(0, 1, colk1)
            P_OPEN() MFMA16(1) VM(8); P_CLOSE()
        }
        {   // tile t+1 (buf1): stage B(t+2)->buf0, A(t+2)->buf0, issue A(t+3)
            bf16x8 afr[4], bfr[4];
            RD_B(1, colk0) RD_A(1, 0, colk0) B_GLDS(t + 2, 0)
            P_OPEN() MFMA16(0) P_CLOSE()
            RD_A(1, 1, colk0) A_WRITE(0)
            P_OPEN() MFMA16(1) P_CLOSE()
            RD_B(1, colk1) RD_A(1, 0, colk1) A_ISSUE(t + 3)
            P_OPEN() MFMA16(0) P_CLOSE()
            RD_A(1, 1, colk1)
            P_OPEN() MFMA16(1) VM(8); P_CLOSE()
        }
    }
    {   // tile 14 (buf0): stage B(15)->buf1, A(15)->buf1; nothing to issue
        bf16x8 afr[4], bfr[4];
        RD_B(0, colk0) RD_A(0, 0, colk0) B_GLDS(15, 1)
        P_OPEN() MFMA16(0) P_CLOSE()
        RD_A(0, 1, colk0) A_WRITE(1)
        P_OPEN() MFMA16(1) P_CLOSE()
        RD_B(0, colk1) RD_A(0, 0, colk1)
        P_OPEN() MFMA16(0) P_CLOSE()
        RD_A(0, 1, colk1)
        P_OPEN() MFMA16(1) VM(0); P_CLOSE()
    }
    {   // tile 15 (buf1): compute only
        bf16x8 afr[4], bfr[4];
        RD_B(1, colk0) RD_A(1, 0, colk0)
        P_OPEN() MFMA16(0) P_CLOSE()
        RD_A(1, 1, colk0)
        P_OPEN() MFMA16(1) P_CLOSE()
        RD_B(1, colk1) RD_A(1, 0, colk1)
        P_OPEN() MFMA16(0) P_CLOSE()
        RD_A(1, 1, colk1)
        P_OPEN() MFMA16(1) P_CLOSE()
    }

    // ------------------- epilogue: tanh + dot(W_v) reduction ----------------
    const int bidx = row0 >> 11;            // 256-row tiles never straddle batch
    float hlv[4], wcv[4], wvv[4];
#pragma unroll
    for (int n = 0; n < 4; ++n) {
        int g = col0 + wcB + n * 16 + lr;
        hlv[n] = hl_plus[bidx * HIDDEN + g];
        wcv[n] = W_cov[g];
        wvv[n] = W_v[g];
    }
#pragma unroll
    for (int am = 0; am < 8; ++am) {
#pragma unroll
        for (int i = 0; i < 4; ++i) {
            int rloc = wrB + am * 16 + kb * 4 + i;
            float cv = cov[row0 + rloc];
            float ep = 0.f;
#pragma unroll
            for (int n = 0; n < 4; ++n) {
                float arg = acc[am][n][i] + hlv[n] + cv * wcv[n];
                ep += tanh_fast(arg) * wvv[n];
            }
            ep += __shfl_xor(ep, 1);
            ep += __shfl_xor(ep, 2);
            ep += __shfl_xor(ep, 4);
            ep += __shfl_xor(ep, 8);
            if (lr == 0) e_buf[rloc][wc] = ep;
        }
    }
    __syncthreads();
    if (tid < 256)
        e_part[(size_t)nt * M_TOT + row0 + tid] =
            e_buf[tid][0] + e_buf[tid][1] + e_buf[tid][2] + e_buf[tid][3];

#undef A_ISSUE
#undef A_WRITE
#undef B_GLDS
#undef RD_A
#undef RD_B
#undef MFMA16
}

// ---------------------------------------------------------------------------
// Kernel 3: per-batch softmax over S=2048; also emits cov_new = cov + a
// ---------------------------------------------------------------------------
__global__ __launch_bounds__(256) void k_softmax(
    const float* __restrict__ e_part, const float* __restrict__ mask,
    const float* __restrict__ cov, const float* __restrict__ b_v,
    float* __restrict__ a_out, float* __restrict__ cov_out)
{
    __shared__ float red[8];
    int b = blockIdx.x, tid = threadIdx.x;
    float bv = b_v[0];
    float ev[8];
    float mx = -1e30f;
#pragma unroll
    for (int j = 0; j < 8; ++j) {
        int s = j * 256 + tid;
        int idx = b * S_SZ + s;
        float e = bv;
#pragma unroll
        for (int p = 0; p < 4; ++p) e += e_part[(size_t)p * M_TOT + idx];
        e += mask[idx] * MASKED_BIAS;
        ev[j] = e;
        mx = fmaxf(mx, e);
    }
#pragma unroll
    for (int off = 32; off; off >>= 1) mx = fmaxf(mx, __shfl_xor(mx, off));
    if ((tid & 63) == 0) red[tid >> 6] = mx;
    __syncthreads();
    mx = fmaxf(fmaxf(red[0], red[1]), fmaxf(red[2], red[3]));
    float sum = 0.f;
#pragma unroll
    for (int j = 0; j < 8; ++j) { ev[j] = __expf(ev[j] - mx); sum += ev[j]; }
#pragma unroll
    for (int off = 32; off; off >>= 1) sum += __shfl_xor(sum, off);
    if ((tid & 63) == 0) red[4 + (tid >> 6)] = sum;
    __syncthreads();
    sum = red[4] + red[5] + red[6] + red[7];
    float inv = 1.f / sum;
#pragma unroll
    for (int j = 0; j < 8; ++j) {
        int idx = b * S_SZ + j * 256 + tid;
        float a = ev[j] * inv;
        a_out[idx]   = a;
        cov_out[idx] = cov[idx] + a;
    }
}

// ---------------------------------------------------------------------------
// Kernel 4: context partials  part_out[b][sc][h] = sum_{s in chunk} a*K
// ---------------------------------------------------------------------------
__global__ __launch_bounds__(256) void k_ctx_part(
    const float* __restrict__ Kin, const float* __restrict__ a_out,
    float* __restrict__ part_out)
{
    int sc = blockIdx.x;   // 0..7
    int b  = blockIdx.y;   // 0..31
    int tid = threadIdx.x;
    const float4* Kb = (const float4*)(Kin + ((size_t)b * S_SZ + sc * 256) * HIDDEN);
    const float*  ab = a_out + b * S_SZ + sc * 256;
    float4 acc = {0.f, 0.f, 0.f, 0.f};
#pragma unroll 4
    for (int s = 0; s < 256; ++s) {
        float av = ab[s];
        float4 kv = Kb[(size_t)s * 256 + tid];
        acc.x += av * kv.x; acc.y += av * kv.y;
        acc.z += av * kv.z; acc.w += av * kv.w;
    }
    ((float4*)part_out)[((size_t)b * 8 + sc) * 256 + tid] = acc;
}

// ---------------------------------------------------------------------------
// Kernel 5: out[b][h] = sum_sc part_out[b][sc][h]
// ---------------------------------------------------------------------------
__global__ __launch_bounds__(256) void k_ctx_reduce(
    const float* __restrict__ part_out, float* __restrict__ out)
{
    int b = blockIdx.x, tid = threadIdx.x;
    float4 acc = {0.f, 0.f, 0.f, 0.f};
#pragma unroll
    for (int sc = 0; sc < 8; ++sc) {
        float4 v = ((const float4*)part_out)[((size_t)b * 8 + sc) * 256 + tid];
        acc.x += v.x; acc.y += v.y; acc.z += v.z; acc.w += v.w;
    }
    ((float4*)out)[b * 256 + tid] = acc;
}

// ---------------------------------------------------------------------------
extern "C" void kernel_launch(void* const* d_in, const int* in_sizes, int n_in,
                              void* d_out, int out_size, void* d_ws, size_t ws_size,
                              hipStream_t stream)
{
    const float* h     = (const float*)d_in[0];
    const float* Kin   = (const float*)d_in[1];
    const float* cov   = (const float*)d_in[2];
    const float* mask  = (const float*)d_in[3];
    const float* W_h   = (const float*)d_in[4];
    const float* b_h   = (const float*)d_in[5];
    const float* W_K   = (const float*)d_in[6];
    const float* b_K   = (const float*)d_in[7];
    const float* W_cov = (const float*)d_in[8];
    const float* b_cov = (const float*)d_in[9];
    const float* W_v   = (const float*)d_in[10];
    const float* b_v   = (const float*)d_in[11];

    float* out_ctx = (float*)d_out;            // 32*1024
    float* a_out   = out_ctx + B_SZ * HIDDEN;  // 32*2048
    float* cov_out = a_out + M_TOT;            // 32*2048

    float* ws       = (float*)d_ws;
    float* hl_plus  = ws;                        // 32768 f32
    float* e_part   = ws + 32768;                // 4*65536 f32
    float* part_out = e_part;                    // aliases e_part (sequential use)
    bf16*  Bbf      = (bf16*)(e_part + 4 * M_TOT);  // 1024*1024 bf16
    // total ws use: ~3.2 MB

    k_wconv<<<512, 256, 0, stream>>>(W_K, Bbf);
    k_hlplus<<<8192, 256, 0, stream>>>(h, W_h, b_h, b_K, b_cov, hl_plus);
    k_fused<<<256 * NT_N, 512, 0, stream>>>(
        Kin, Bbf, hl_plus, W_cov, cov, W_v, e_part);
    k_softmax<<<B_SZ, 256, 0, stream>>>(e_part, mask, cov, b_v, a_out, cov_out);
    dim3 g4(8, B_SZ);
    k_ctx_part<<<g4, 256, 0, stream>>>(Kin, a_out, part_out);
    k_ctx_reduce<<<B_SZ, 256, 0, stream>>>(part_out, out_ctx);
}

// Round 6
// 320.773 us; speedup vs baseline: 1.1292x; 1.1292x over previous
//
#include <hip/hip_runtime.h>
#include <hip/hip_bf16.h>

#define HIDDEN 1024
#define B_SZ 32
#define S_SZ 2048
#define M_TOT (B_SZ * S_SZ)          // 65536 rows
#define MASKED_BIAS -10000.0f

using bf16   = __bf16;
using bf16x4 = __attribute__((ext_vector_type(4))) __bf16;
using bf16x8 = __attribute__((ext_vector_type(8))) __bf16;
using f32x4  = __attribute__((ext_vector_type(4))) float;

__device__ __forceinline__ float tanh_fast(float x) {
    float xc = fminf(fmaxf(x, -15.f), 15.f);
    float e2 = __expf(2.f * xc);
    return (e2 - 1.f) * __frcp_rn(e2 + 1.f);
}

// ---------------------------------------------------------------------------
// Kernel 0a: W_K f32 -> bf16 (2 MB, L2-resident B operand)
// ---------------------------------------------------------------------------
__global__ __launch_bounds__(256) void k_wconv(
    const float* __restrict__ W, bf16* __restrict__ out)
{
    int i = blockIdx.x * 256 + threadIdx.x;      // 131072 threads x 8 elems
    const float4* p = (const float4*)W + (size_t)i * 2;
    float4 a = p[0], b = p[1];
    bf16x8 v = { (bf16)a.x, (bf16)a.y, (bf16)a.z, (bf16)a.w,
                 (bf16)b.x, (bf16)b.y, (bf16)b.z, (bf16)b.w };
    *(bf16x8*)(out + (size_t)i * 8) = v;
}

// ---------------------------------------------------------------------------
// Kernel 0b: K f32 -> bf16 (128 MB A operand; enables global_load_lds staging)
// ---------------------------------------------------------------------------
__global__ __launch_bounds__(256) void k_kconv(
    const float* __restrict__ K, bf16* __restrict__ out)
{
    size_t i = (size_t)blockIdx.x * 256 + threadIdx.x;   // 8M threads x 8 elems
    const float4* p = (const float4*)K + i * 2;
    float4 a = p[0], b = p[1];
    bf16x8 v = { (bf16)a.x, (bf16)a.y, (bf16)a.z, (bf16)a.w,
                 (bf16)b.x, (bf16)b.y, (bf16)b.z, (bf16)b.w };
    *(bf16x8*)(out + i * 8) = v;
}

// ---------------------------------------------------------------------------
// Kernel 1: hl_plus[b][g] = dot(h[b,:], W_h[g,:]) + b_h[g] + b_K[g] + b_cov[g]
// ---------------------------------------------------------------------------
__global__ __launch_bounds__(256) void k_hlplus(
    const float* __restrict__ h, const float* __restrict__ W_h,
    const float* __restrict__ b_h, const float* __restrict__ b_K,
    const float* __restrict__ b_cov, float* __restrict__ hl_plus)
{
    int wid  = blockIdx.x * 4 + (threadIdx.x >> 6);  // 0..32767
    int lane = threadIdx.x & 63;
    int b = wid & 31;
    int g = wid >> 5;
    const float4* hv = (const float4*)(h + b * HIDDEN);
    const float4* wv = (const float4*)(W_h + g * HIDDEN);
    float acc = 0.f;
#pragma unroll
    for (int i = 0; i < 4; ++i) {
        float4 a = hv[i * 64 + lane];
        float4 w = wv[i * 64 + lane];
        acc += a.x * w.x + a.y * w.y + a.z * w.z + a.w * w.w;
    }
#pragma unroll
    for (int off = 32; off; off >>= 1) acc += __shfl_xor(acc, off);
    if (lane == 0)
        hl_plus[b * HIDDEN + g] = acc + b_h[g] + b_K[g] + b_cov[g];
}

// ===========================================================================
// Kernel 2 (primary): fused GEMM, A AND B staged via global_load_lds from
// bf16 sources. 256x256 tile, BK=64, 8 waves, 4 phases per K-tile.
// Prefetch: tile t+1's A gloads at ph1, B gloads at ph2 of tile t; VM(0) at
// ph4 (~3 phases of flight). XOR involution on the gload SOURCE, swizzled
// ds_read (rule #21). setprio around MFMA (T5), XCD-bijective swizzle (T1).
// ===========================================================================
#define NT_N 4

__global__ __launch_bounds__(512) void k_fused_g(
    const bf16*  __restrict__ Kbf,      // [65536][1024] bf16
    const bf16*  __restrict__ Bbf,      // [1024][1024] bf16 (W_K)
    const float* __restrict__ hl_plus,
    const float* __restrict__ W_cov,
    const float* __restrict__ cov,
    const float* __restrict__ W_v,
    float* __restrict__ e_part)         // [4][65536]
{
    __shared__ __align__(16) bf16 AsT[2][256][64];
    __shared__ __align__(16) bf16 BsT[2][256][64];
    __shared__ float e_buf[256][4];

    const int tid = threadIdx.x;
    const int bid = blockIdx.x;
    const int lid = (bid & 7) * 128 + (bid >> 3);   // 1024 blocks, bijective
    const int mt  = lid >> 2;
    const int nt  = lid & 3;
    const int row0 = mt * 256;
    const int col0 = nt * 256;

    const int w    = tid >> 6;
    const int lane = tid & 63;
    const int wr   = w >> 2;
    const int wc   = w & 3;
    const int lr   = lane & 15;
    const int kb   = lane >> 4;
    const int wrB  = wr * 128;
    const int wcB  = wc * 64;
    const int colk0 = (kb ^ (lr & 7)) * 8;
    const int colk1 = ((4 + kb) ^ (lr & 7)) * 8;

    // gload geometry: lane l -> LDS row (w*4+j)*8 + (l>>3), 16B slot l&7;
    // source chunk pre-swizzled: slot s holds global chunk s ^ (row&7)
    const int brow_l = lane >> 3;
    const int bcl    = (lane & 7) ^ brow_l;

    f32x4 acc[8][4] = {};

#define GLDS_A(kt, BUF)                                                   \
    _Pragma("unroll") for (int j = 0; j < 4; ++j) {                       \
        const bf16* gs_ = Kbf +                                           \
            (size_t)(row0 + (w * 4 + j) * 8 + brow_l) * HIDDEN +          \
            (kt) * 64 + bcl * 8;                                          \
        __builtin_amdgcn_global_load_lds(                                 \
            (const __attribute__((address_space(1))) void*)gs_,           \
            (__attribute__((address_space(3))) void*)&AsT[BUF][(w * 4 + j) * 8][0], \
            16, 0, 0);                                                    \
    }

#define GLDS_B(kt, BUF)                                                   \
    _Pragma("unroll") for (int j = 0; j < 4; ++j) {                       \
        const bf16* gs_ = Bbf +                                           \
            (size_t)(col0 + (w * 4 + j) * 8 + brow_l) * HIDDEN +          \
            (kt) * 64 + bcl * 8;                                          \
        __builtin_amdgcn_global_load_lds(                                 \
            (const __attribute__((address_space(1))) void*)gs_,           \
            (__attribute__((address_space(3))) void*)&BsT[BUF][(w * 4 + j) * 8][0], \
            16, 0, 0);                                                    \
    }

#define RD_A(BUF, MP, COLK)                                               \
    _Pragma("unroll") for (int j = 0; j < 4; ++j)                         \
        afr[j] = *(const bf16x8*)&AsT[BUF][wrB + (MP) * 64 + j * 16 + lr][COLK];

#define RD_B(BUF, COLK)                                                   \
    _Pragma("unroll") for (int n = 0; n < 4; ++n)                         \
        bfr[n] = *(const bf16x8*)&BsT[BUF][wcB + n * 16 + lr][COLK];

#define MFMA16(MP)                                                        \
    __builtin_amdgcn_s_setprio(1);                                        \
    _Pragma("unroll") for (int j = 0; j < 4; ++j)                         \
        _Pragma("unroll") for (int n = 0; n < 4; ++n)                     \
            acc[(MP) * 4 + j][n] = __builtin_amdgcn_mfma_f32_16x16x32_bf16( \
                afr[j], bfr[n], acc[(MP) * 4 + j][n], 0, 0, 0);           \
    __builtin_amdgcn_s_setprio(0);

#define MEMBAR() asm volatile("" ::: "memory")
#define LGKM0()  asm volatile("s_waitcnt lgkmcnt(0)" ::: "memory")
#define VM0()    asm volatile("s_waitcnt vmcnt(0)" ::: "memory")
#define SBAR()   __builtin_amdgcn_s_barrier()
#define P_OPEN()  MEMBAR(); SBAR(); LGKM0();
#define P_CLOSE() MEMBAR(); SBAR();

    // ---- prologue: stage tile 0 into buf0 ----
    GLDS_A(0, 0)
    GLDS_B(0, 0)
    VM0();
    MEMBAR(); SBAR();

    // ---- main loop: 2 tiles per iteration, tiles 0..13 ----
    for (int kt2 = 0; kt2 < 7; ++kt2) {
        const int t = kt2 * 2;
        {   // tile t (buf0), stage t+1 -> buf1
            bf16x8 afr[4], bfr[4];
            RD_B(0, colk0) RD_A(0, 0, colk0) GLDS_A(t + 1, 1)
            P_OPEN() MFMA16(0) P_CLOSE()
            RD_A(0, 1, colk0) GLDS_B(t + 1, 1)
            P_OPEN() MFMA16(1) P_CLOSE()
            RD_B(0, colk1) RD_A(0, 0, colk1)
            P_OPEN() MFMA16(0) P_CLOSE()
            RD_A(0, 1, colk1)
            P_OPEN() MFMA16(1) VM0(); P_CLOSE()
        }
        {   // tile t+1 (buf1), stage t+2 -> buf0
            bf16x8 afr[4], bfr[4];
            RD_B(1, colk0) RD_A(1, 0, colk0) GLDS_A(t + 2, 0)
            P_OPEN() MFMA16(0) P_CLOSE()
            RD_A(1, 1, colk0) GLDS_B(t + 2, 0)
            P_OPEN() MFMA16(1) P_CLOSE()
            RD_B(1, colk1) RD_A(1, 0, colk1)
            P_OPEN() MFMA16(0) P_CLOSE()
            RD_A(1, 1, colk1)
            P_OPEN() MFMA16(1) VM0(); P_CLOSE()
        }
    }
    {   // tile 14 (buf0), stage 15 -> buf1
        bf16x8 afr[4], bfr[4];
        RD_B(0, colk0) RD_A(0, 0, colk0) GLDS_A(15, 1)
        P_OPEN() MFMA16(0) P_CLOSE()
        RD_A(0, 1, colk0) GLDS_B(15, 1)
        P_OPEN() MFMA16(1) P_CLOSE()
        RD_B(0, colk1) RD_A(0, 0, colk1)
        P_OPEN() MFMA16(0) P_CLOSE()
        RD_A(0, 1, colk1)
        P_OPEN() MFMA16(1) VM0(); P_CLOSE()
    }
    {   // tile 15 (buf1), compute only
        bf16x8 afr[4], bfr[4];
        RD_B(1, colk0) RD_A(1, 0, colk0)
        P_OPEN() MFMA16(0) P_CLOSE()
        RD_A(1, 1, colk0)
        P_OPEN() MFMA16(1) P_CLOSE()
        RD_B(1, colk1) RD_A(1, 0, colk1)
        P_OPEN() MFMA16(0) P_CLOSE()
        RD_A(1, 1, colk1)
        P_OPEN() MFMA16(1) P_CLOSE()
    }

    // ------------------- epilogue: tanh + dot(W_v) reduction ----------------
    const int bidx = row0 >> 11;
    float hlv[4], wcv[4], wvv[4];
#pragma unroll
    for (int n = 0; n < 4; ++n) {
        int g = col0 + wcB + n * 16 + lr;
        hlv[n] = hl_plus[bidx * HIDDEN + g];
        wcv[n] = W_cov[g];
        wvv[n] = W_v[g];
    }
#pragma unroll
    for (int am = 0; am < 8; ++am) {
#pragma unroll
        for (int i = 0; i < 4; ++i) {
            int rloc = wrB + am * 16 + kb * 4 + i;
            float cv = cov[row0 + rloc];
            float ep = 0.f;
#pragma unroll
            for (int n = 0; n < 4; ++n) {
                float arg = acc[am][n][i] + hlv[n] + cv * wcv[n];
                ep += tanh_fast(arg) * wvv[n];
            }
            ep += __shfl_xor(ep, 1);
            ep += __shfl_xor(ep, 2);
            ep += __shfl_xor(ep, 4);
            ep += __shfl_xor(ep, 8);
            if (lr == 0) e_buf[rloc][wc] = ep;
        }
    }
    __syncthreads();
    if (tid < 256)
        e_part[(size_t)nt * M_TOT + row0 + tid] =
            e_buf[tid][0] + e_buf[tid][1] + e_buf[tid][2] + e_buf[tid][3];

#undef GLDS_A
#undef GLDS_B
#undef RD_A
#undef RD_B
#undef MFMA16
#undef MEMBAR
#undef LGKM0
#undef VM0
#undef SBAR
#undef P_OPEN
#undef P_CLOSE
}

// ===========================================================================
// Kernel 2 (fallback, R5 verbatim): used only if ws_size can't hold Kbf.
// ===========================================================================
__global__ __launch_bounds__(512) void k_fused_rs(
    const float* __restrict__ Kin,
    const bf16*  __restrict__ Bbf,
    const float* __restrict__ hl_plus,
    const float* __restrict__ W_cov,
    const float* __restrict__ cov,
    const float* __restrict__ W_v,
    float* __restrict__ e_part)
{
    __shared__ __align__(16) bf16 AsT[2][256][64];
    __shared__ __align__(16) bf16 BsT[2][256][64];
    __shared__ float e_buf[256][4];

    const int tid = threadIdx.x;
    const int bid = blockIdx.x;
    const int lid = (bid & 7) * 128 + (bid >> 3);
    const int mt  = lid >> 2;
    const int nt  = lid & 3;
    const int row0 = mt * 256;
    const int col0 = nt * 256;

    const int w    = tid >> 6;
    const int lane = tid & 63;
    const int wr   = w >> 2;
    const int wc   = w & 3;
    const int lr   = lane & 15;
    const int kb   = lane >> 4;
    const int wrB  = wr * 128;
    const int wcB  = wc * 64;
    const int colk0 = (kb ^ (lr & 7)) * 8;
    const int colk1 = ((4 + kb) ^ (lr & 7)) * 8;

    const int arow  = tid >> 1;
    const int ahalf = tid & 1;
    const float4* Asrc =
        (const float4*)(Kin + (size_t)(row0 + arow) * HIDDEN + ahalf * 32);
    const int brow_l = lane >> 3;
    const int bcl    = (lane & 7) ^ brow_l;

    float4 aR[8];
    f32x4 acc[8][4] = {};

#define A_ISSUE(kt)                                                       \
    { const float4* p_ = Asrc + (kt) * 16;                                \
      _Pragma("unroll") for (int j = 0; j < 8; ++j) aR[j] = p_[j]; }

#define A_WRITE(BUF)                                                      \
    _Pragma("unroll") for (int j2 = 0; j2 < 4; ++j2) {                    \
        float4 u_ = aR[j2 * 2], v_ = aR[j2 * 2 + 1];                      \
        bf16x8 w8_ = { (bf16)u_.x, (bf16)u_.y, (bf16)u_.z, (bf16)u_.w,    \
                       (bf16)v_.x, (bf16)v_.y, (bf16)v_.z, (bf16)v_.w };  \
        int cl_ = (ahalf * 4 + j2) ^ (arow & 7);                          \
        *(bf16x8*)&AsT[BUF][arow][cl_ * 8] = w8_;                         \
    }

#define B_GLDS(kt, BUF)                                                   \
    _Pragma("unroll") for (int j = 0; j < 4; ++j) {                       \
        const bf16* gs_ = Bbf +                                           \
            (size_t)(col0 + (w * 4 + j) * 8 + brow_l) * HIDDEN +          \
            (kt) * 64 + bcl * 8;                                          \
        __builtin_amdgcn_global_load_lds(                                 \
            (const __attribute__((address_space(1))) void*)gs_,           \
            (__attribute__((address_space(3))) void*)&BsT[BUF][(w * 4 + j) * 8][0], \
            16, 0, 0);                                                    \
    }

#define RD_A(BUF, MP, COLK)                                               \
    _Pragma("unroll") for (int j = 0; j < 4; ++j)                         \
        afr[j] = *(const bf16x8*)&AsT[BUF][wrB + (MP) * 64 + j * 16 + lr][COLK];

#define RD_B(BUF, COLK)                                                   \
    _Pragma("unroll") for (int n = 0; n < 4; ++n)                         \
        bfr[n] = *(const bf16x8*)&BsT[BUF][wcB + n * 16 + lr][COLK];

#define MFMA16(MP)                                                        \
    __builtin_amdgcn_s_setprio(1);                                        \
    _Pragma("unroll") for (int j = 0; j < 4; ++j)                         \
        _Pragma("unroll") for (int n = 0; n < 4; ++n)                     \
            acc[(MP) * 4 + j][n] = __builtin_amdgcn_mfma_f32_16x16x32_bf16( \
                afr[j], bfr[n], acc[(MP) * 4 + j][n], 0, 0, 0);           \
    __builtin_amdgcn_s_setprio(0);

#define MEMBAR() asm volatile("" ::: "memory")
#define LGKM0()  asm volatile("s_waitcnt lgkmcnt(0)" ::: "memory")
#define VM(n)    asm volatile("s_waitcnt vmcnt(" #n ")" ::: "memory")
#define SBAR()   __builtin_amdgcn_s_barrier()
#define P_OPEN()  MEMBAR(); SBAR(); LGKM0();
#define P_CLOSE() MEMBAR(); SBAR();

    A_ISSUE(0)
    B_GLDS(0, 0)
    A_WRITE(0)
    A_ISSUE(1)
    VM(8);
    LGKM0();
    MEMBAR(); SBAR();

    for (int kt2 = 0; kt2 < 7; ++kt2) {
        const int t = kt2 * 2;
        {
            bf16x8 afr[4], bfr[4];
            RD_B(0, colk0) RD_A(0, 0, colk0) B_GLDS(t + 1, 1)
            P_OPEN() MFMA16(0) P_CLOSE()
            RD_A(0, 1, colk0) A_WRITE(1)
            P_OPEN() MFMA16(1) P_CLOSE()
            RD_B(0, colk1) RD_A(0, 0, colk1) A_ISSUE(t + 2)
            P_OPEN() MFMA16(0) P_CLOSE()
            RD_A(0, 1, colk1)
            P_OPEN() MFMA16(1) VM(8); P_CLOSE()
        }
        {
            bf16x8 afr[4], bfr[4];
            RD_B(1, colk0) RD_A(1, 0, colk0) B_GLDS(t + 2, 0)
            P_OPEN() MFMA16(0) P_CLOSE()
            RD_A(1, 1, colk0) A_WRITE(0)
            P_OPEN() MFMA16(1) P_CLOSE()
            RD_B(1, colk1) RD_A(1, 0, colk1) A_ISSUE(t + 3)
            P_OPEN() MFMA16(0) P_CLOSE()
            RD_A(1, 1, colk1)
            P_OPEN() MFMA16(1) VM(8); P_CLOSE()
        }
    }
    {
        bf16x8 afr[4], bfr[4];
        RD_B(0, colk0) RD_A(0, 0, colk0) B_GLDS(15, 1)
        P_OPEN() MFMA16(0) P_CLOSE()
        RD_A(0, 1, colk0) A_WRITE(1)
        P_OPEN() MFMA16(1) P_CLOSE()
        RD_B(0, colk1) RD_A(0, 0, colk1)
        P_OPEN() MFMA16(0) P_CLOSE()
        RD_A(0, 1, colk1)
        P_OPEN() MFMA16(1) VM(0); P_CLOSE()
    }
    {
        bf16x8 afr[4], bfr[4];
        RD_B(1, colk0) RD_A(1, 0, colk0)
        P_OPEN() MFMA16(0) P_CLOSE()
        RD_A(1, 1, colk0)
        P_OPEN() MFMA16(1) P_CLOSE()
        RD_B(1, colk1) RD_A(1, 0, colk1)
        P_OPEN() MFMA16(0) P_CLOSE()
        RD_A(1, 1, colk1)
        P_OPEN() MFMA16(1) P_CLOSE()
    }

    const int bidx = row0 >> 11;
    float hlv[4], wcv[4], wvv[4];
#pragma unroll
    for (int n = 0; n < 4; ++n) {
        int g = col0 + wcB + n * 16 + lr;
        hlv[n] = hl_plus[bidx * HIDDEN + g];
        wcv[n] = W_cov[g];
        wvv[n] = W_v[g];
    }
#pragma unroll
    for (int am = 0; am < 8; ++am) {
#pragma unroll
        for (int i = 0; i < 4; ++i) {
            int rloc = wrB + am * 16 + kb * 4 + i;
            float cv = cov[row0 + rloc];
            float ep = 0.f;
#pragma unroll
            for (int n = 0; n < 4; ++n) {
                float arg = acc[am][n][i] + hlv[n] + cv * wcv[n];
                ep += tanh_fast(arg) * wvv[n];
            }
            ep += __shfl_xor(ep, 1);
            ep += __shfl_xor(ep, 2);
            ep += __shfl_xor(ep, 4);
            ep += __shfl_xor(ep, 8);
            if (lr == 0) e_buf[rloc][wc] = ep;
        }
    }
    __syncthreads();
    if (tid < 256)
        e_part[(size_t)nt * M_TOT + row0 + tid] =
            e_buf[tid][0] + e_buf[tid][1] + e_buf[tid][2] + e_buf[tid][3];

#undef A_ISSUE
#undef A_WRITE
#undef B_GLDS
#undef RD_A
#undef RD_B
#undef MFMA16
#undef MEMBAR
#undef LGKM0
#undef VM
#undef SBAR
#undef P_OPEN
#undef P_CLOSE
}

// ---------------------------------------------------------------------------
// Kernel 3: per-batch softmax over S=2048; also emits cov_new = cov + a
// ---------------------------------------------------------------------------
__global__ __launch_bounds__(256) void k_softmax(
    const float* __restrict__ e_part, const float* __restrict__ mask,
    const float* __restrict__ cov, const float* __restrict__ b_v,
    float* __restrict__ a_out, float* __restrict__ cov_out)
{
    __shared__ float red[8];
    int b = blockIdx.x, tid = threadIdx.x;
    float bv = b_v[0];
    float ev[8];
    float mx = -1e30f;
#pragma unroll
    for (int j = 0; j < 8; ++j) {
        int s = j * 256 + tid;
        int idx = b * S_SZ + s;
        float e = bv;
#pragma unroll
        for (int p = 0; p < 4; ++p) e += e_part[(size_t)p * M_TOT + idx];
        e += mask[idx] * MASKED_BIAS;
        ev[j] = e;
        mx = fmaxf(mx, e);
    }
#pragma unroll
    for (int off = 32; off; off >>= 1) mx = fmaxf(mx, __shfl_xor(mx, off));
    if ((tid & 63) == 0) red[tid >> 6] = mx;
    __syncthreads();
    mx = fmaxf(fmaxf(red[0], red[1]), fmaxf(red[2], red[3]));
    float sum = 0.f;
#pragma unroll
    for (int j = 0; j < 8; ++j) { ev[j] = __expf(ev[j] - mx); sum += ev[j]; }
#pragma unroll
    for (int off = 32; off; off >>= 1) sum += __shfl_xor(sum, off);
    if ((tid & 63) == 0) red[4 + (tid >> 6)] = sum;
    __syncthreads();
    sum = red[4] + red[5] + red[6] + red[7];
    float inv = 1.f / sum;
#pragma unroll
    for (int j = 0; j < 8; ++j) {
        int idx = b * S_SZ + j * 256 + tid;
        float a = ev[j] * inv;
        a_out[idx]   = a;
        cov_out[idx] = cov[idx] + a;
    }
}

// ---------------------------------------------------------------------------
// Kernel 4: context partials  part_out[b][sc][h] = sum_{s in chunk} a*K
// ---------------------------------------------------------------------------
__global__ __launch_bounds__(256) void k_ctx_part(
    const float* __restrict__ Kin, const float* __restrict__ a_out,
    float* __restrict__ part_out)
{
    int sc = blockIdx.x;
    int b  = blockIdx.y;
    int tid = threadIdx.x;
    const float4* Kb = (const float4*)(Kin + ((size_t)b * S_SZ + sc * 256) * HIDDEN);
    const float*  ab = a_out + b * S_SZ + sc * 256;
    float4 acc = {0.f, 0.f, 0.f, 0.f};
#pragma unroll 4
    for (int s = 0; s < 256; ++s) {
        float av = ab[s];
        float4 kv = Kb[(size_t)s * 256 + tid];
        acc.x += av * kv.x; acc.y += av * kv.y;
        acc.z += av * kv.z; acc.w += av * kv.w;
    }
    ((float4*)part_out)[((size_t)b * 8 + sc) * 256 + tid] = acc;
}

// ---------------------------------------------------------------------------
// Kernel 5: out[b][h] = sum_sc part_out[b][sc][h]
// ---------------------------------------------------------------------------
__global__ __launch_bounds__(256) void k_ctx_reduce(
    const float* __restrict__ part_out, float* __restrict__ out)
{
    int b = blockIdx.x, tid = threadIdx.x;
    float4 acc = {0.f, 0.f, 0.f, 0.f};
#pragma unroll
    for (int sc = 0; sc < 8; ++sc) {
        float4 v = ((const float4*)part_out)[((size_t)b * 8 + sc) * 256 + tid];
        acc.x += v.x; acc.y += v.y; acc.z += v.z; acc.w += v.w;
    }
    ((float4*)out)[b * 256 + tid] = acc;
}

// ---------------------------------------------------------------------------
extern "C" void kernel_launch(void* const* d_in, const int* in_sizes, int n_in,
                              void* d_out, int out_size, void* d_ws, size_t ws_size,
                              hipStream_t stream)
{
    const float* h     = (const float*)d_in[0];
    const float* Kin   = (const float*)d_in[1];
    const float* cov   = (const float*)d_in[2];
    const float* mask  = (const float*)d_in[3];
    const float* W_h   = (const float*)d_in[4];
    const float* b_h   = (const float*)d_in[5];
    const float* W_K   = (const float*)d_in[6];
    const float* b_K   = (const float*)d_in[7];
    const float* W_cov = (const float*)d_in[8];
    const float* b_cov = (const float*)d_in[9];
    const float* W_v   = (const float*)d_in[10];
    const float* b_v   = (const float*)d_in[11];

    float* out_ctx = (float*)d_out;            // 32*1024
    float* a_out   = out_ctx + B_SZ * HIDDEN;  // 32*2048
    float* cov_out = a_out + M_TOT;            // 32*2048

    float* ws       = (float*)d_ws;
    float* hl_plus  = ws;                        // 32768 f32
    float* e_part   = ws + 32768;                // 4*65536 f32
    float* part_out = e_part;                    // aliases e_part (sequential use)
    bf16*  Bbf      = (bf16*)(e_part + 4 * M_TOT);          // 1 Mi bf16 = 2 MB
    bf16*  Kbf      = (bf16*)((char*)Bbf + (size_t)HIDDEN * HIDDEN * sizeof(bf16));
    const size_t need_big =
        (size_t)(32768 + 4 * M_TOT) * 4 +
        (size_t)HIDDEN * HIDDEN * 2 +
        (size_t)M_TOT * HIDDEN * 2;              // ~131.3 MB

    k_wconv<<<512, 256, 0, stream>>>(W_K, Bbf);
    k_hlplus<<<8192, 256, 0, stream>>>(h, W_h, b_h, b_K, b_cov, hl_plus);

    if (ws_size >= need_big) {
        k_kconv<<<(M_TOT * HIDDEN / 8) / 256, 256, 0, stream>>>(Kin, Kbf);
        k_fused_g<<<256 * NT_N, 512, 0, stream>>>(
            Kbf, Bbf, hl_plus, W_cov, cov, W_v, e_part);
    } else {
        k_fused_rs<<<256 * NT_N, 512, 0, stream>>>(
            Kin, Bbf, hl_plus, W_cov, cov, W_v, e_part);
    }

    k_softmax<<<B_SZ, 256, 0, stream>>>(e_part, mask, cov, b_v, a_out, cov_out);
    dim3 g4(8, B_SZ);
    k_ctx_part<<<g4, 256, 0, stream>>>(Kin, a_out, part_out);
    k_ctx_reduce<<<B_SZ, 256, 0, stream>>>(part_out, out_ctx);
}

// Round 7
// 320.116 us; speedup vs baseline: 1.1315x; 1.0021x over previous
//
#include <hip/hip_runtime.h>
#include <hip/hip_bf16.h>

#define HIDDEN 1024
#define B_SZ 32
#define S_SZ 2048
#define M_TOT (B_SZ * S_SZ)          // 65536 rows
#define MASKED_BIAS -10000.0f

using bf16   = __bf16;
using bf16x4 = __attribute__((ext_vector_type(4))) __bf16;
using bf16x8 = __attribute__((ext_vector_type(8))) __bf16;
using f32x4  = __attribute__((ext_vector_type(4))) float;

__device__ __forceinline__ float tanh_fast(float x) {
    float xc = fminf(fmaxf(x, -15.f), 15.f);
    float e2 = __expf(2.f * xc);
    return (e2 - 1.f) * __frcp_rn(e2 + 1.f);
}

// ---------------------------------------------------------------------------
// Kernel 0a: W_K f32 -> bf16 (2 MB, L2-resident B operand)
// ---------------------------------------------------------------------------
__global__ __launch_bounds__(256) void k_wconv(
    const float* __restrict__ W, bf16* __restrict__ out)
{
    int i = blockIdx.x * 256 + threadIdx.x;
    const float4* p = (const float4*)W + (size_t)i * 2;
    float4 a = p[0], b = p[1];
    bf16x8 v = { (bf16)a.x, (bf16)a.y, (bf16)a.z, (bf16)a.w,
                 (bf16)b.x, (bf16)b.y, (bf16)b.z, (bf16)b.w };
    *(bf16x8*)(out + (size_t)i * 8) = v;
}

// ---------------------------------------------------------------------------
// Kernel 0b: K f32 -> bf16 (128 MB A operand)
// ---------------------------------------------------------------------------
__global__ __launch_bounds__(256) void k_kconv(
    const float* __restrict__ K, bf16* __restrict__ out)
{
    size_t i = (size_t)blockIdx.x * 256 + threadIdx.x;
    const float4* p = (const float4*)K + i * 2;
    float4 a = p[0], b = p[1];
    bf16x8 v = { (bf16)a.x, (bf16)a.y, (bf16)a.z, (bf16)a.w,
                 (bf16)b.x, (bf16)b.y, (bf16)b.z, (bf16)b.w };
    *(bf16x8*)(out + i * 8) = v;
}

// ---------------------------------------------------------------------------
// Kernel 1: hl_plus[b][g] = dot(h[b,:], W_h[g,:]) + b_h[g] + b_K[g] + b_cov[g]
// ---------------------------------------------------------------------------
__global__ __launch_bounds__(256) void k_hlplus(
    const float* __restrict__ h, const float* __restrict__ W_h,
    const float* __restrict__ b_h, const float* __restrict__ b_K,
    const float* __restrict__ b_cov, float* __restrict__ hl_plus)
{
    int wid  = blockIdx.x * 4 + (threadIdx.x >> 6);
    int lane = threadIdx.x & 63;
    int b = wid & 31;
    int g = wid >> 5;
    const float4* hv = (const float4*)(h + b * HIDDEN);
    const float4* wv = (const float4*)(W_h + g * HIDDEN);
    float acc = 0.f;
#pragma unroll
    for (int i = 0; i < 4; ++i) {
        float4 a = hv[i * 64 + lane];
        float4 w = wv[i * 64 + lane];
        acc += a.x * w.x + a.y * w.y + a.z * w.z + a.w * w.w;
    }
#pragma unroll
    for (int off = 32; off; off >>= 1) acc += __shfl_xor(acc, off);
    if (lane == 0)
        hl_plus[b * HIDDEN + g] = acc + b_h[g] + b_K[g] + b_cov[g];
}

// ===========================================================================
// Kernel 2: fused GEMM+tanh+dot. 256x256 tile, BK=64 split into 2 half-tiles
// of 32 cols, 8 waves, 4 phases/K-tile. A,B both staged via global_load_lds.
// T4 counted waits: stage half h of tile t+1 at ph(2h+1); wait vmcnt(4) at
// end of ph2/ph4 (oldest half-group done, never drain to 0 in steady state).
// 64B LDS rows; swizzle chunk = kb ^ ((row>>1)&3) -> 2-way (free) reads.
// ===========================================================================
#define NT_N 4

__global__ __launch_bounds__(512) void k_fused_g(
    const bf16*  __restrict__ Kbf,      // [65536][1024] bf16
    const bf16*  __restrict__ Bbf,      // [1024][1024] bf16 (W_K)
    const float* __restrict__ hl_plus,
    const float* __restrict__ W_cov,
    const float* __restrict__ cov,
    const float* __restrict__ W_v,
    float* __restrict__ e_part)         // [4][65536]
{
    __shared__ __align__(16) bf16 AsT[2][2][256][32];   // [dbuf][half] 64 KB
    __shared__ __align__(16) bf16 BsT[2][2][256][32];   // 64 KB
    __shared__ float e_buf[256][4];

    const int tid = threadIdx.x;
    const int bid = blockIdx.x;
    const int lid = (bid & 7) * 128 + (bid >> 3);   // XCD-bijective
    const int mt  = lid >> 2;
    const int nt  = lid & 3;
    const int row0 = mt * 256;
    const int col0 = nt * 256;

    const int w    = tid >> 6;
    const int lane = tid & 63;
    const int wr   = w >> 2;
    const int wc   = w & 3;
    const int lr   = lane & 15;
    const int kb   = lane >> 4;
    const int wrB  = wr * 128;
    const int wcB  = wc * 64;
    // read-side swizzled column (bf16 elems): chunk = kb ^ ((row>>1)&3),
    // and (row>>1)&3 == (lr>>1)&3 for all fragment rows (j*16 offsets).
    const int colA = (kb ^ ((lr >> 1) & 3)) * 8;

    // stage geometry: per instr, 64 lanes cover 16 rows x 4 chunks (64B rows);
    // source chunk pre-swizzled: lane l -> chunk (l&3) ^ ((l>>3)&3)
    const int srow = lane >> 2;
    const int gch  = (lane & 3) ^ ((lane >> 3) & 3);
    const bf16* Abase = Kbf + (size_t)(row0 + w * 32 + srow) * HIDDEN + gch * 8;
    const bf16* Bbase = Bbf + (size_t)(col0 + w * 32 + srow) * HIDDEN + gch * 8;

    f32x4 acc[8][4] = {};

#define STAGE(KT, H, D)                                                   \
    _Pragma("unroll") for (int j = 0; j < 2; ++j) {                       \
        __builtin_amdgcn_global_load_lds(                                 \
            (const __attribute__((address_space(1))) void*)               \
                (Abase + (size_t)j * 16 * HIDDEN + (KT) * 64 + (H) * 32), \
            (__attribute__((address_space(3))) void*)                     \
                &AsT[D][H][w * 32 + j * 16][0], 16, 0, 0);                \
        __builtin_amdgcn_global_load_lds(                                 \
            (const __attribute__((address_space(1))) void*)               \
                (Bbase + (size_t)j * 16 * HIDDEN + (KT) * 64 + (H) * 32), \
            (__attribute__((address_space(3))) void*)                     \
                &BsT[D][H][w * 32 + j * 16][0], 16, 0, 0);                \
    }

#define RD_A(D, H, MP)                                                   \
    _Pragma("unroll") for (int j = 0; j < 4; ++j)                        \
        afr[j] = *(const bf16x8*)                                        \
            &AsT[D][H][wrB + (MP) * 64 + j * 16 + lr][colA];

#define RD_B(D, H)                                                       \
    _Pragma("unroll") for (int n = 0; n < 4; ++n)                        \
        bfr[n] = *(const bf16x8*)&BsT[D][H][wcB + n * 16 + lr][colA];

#define MFMA16(MP)                                                       \
    __builtin_amdgcn_s_setprio(1);                                       \
    _Pragma("unroll") for (int j = 0; j < 4; ++j)                        \
        _Pragma("unroll") for (int n = 0; n < 4; ++n)                    \
            acc[(MP) * 4 + j][n] = __builtin_amdgcn_mfma_f32_16x16x32_bf16( \
                afr[j], bfr[n], acc[(MP) * 4 + j][n], 0, 0, 0);          \
    __builtin_amdgcn_s_setprio(0);

#define MEMBAR() asm volatile("" ::: "memory")
#define LGKM0()  asm volatile("s_waitcnt lgkmcnt(0)" ::: "memory")
#define VM(n)    asm volatile("s_waitcnt vmcnt(" #n ")" ::: "memory")
#define SBAR()   __builtin_amdgcn_s_barrier()
#define P_OPEN()  MEMBAR(); SBAR(); LGKM0();
#define P_CLOSE() MEMBAR(); SBAR();

    // steady-state tile: reads buf D, stages tile KT_NEXT into buf D^1.
    // vmcnt(4) at end of ph2 (ensures S(t,h1) done for ph3) and end of ph4
    // (ensures S(t+1,h0) done for next tile's ph1). Never 0.
#define TILE_STEADY(D, KT_NEXT)                                          \
    {                                                                    \
        bf16x8 afr[4], bfr[4];                                           \
        RD_B(D, 0) RD_A(D, 0, 0) STAGE(KT_NEXT, 0, D ^ 1)                \
        P_OPEN() MFMA16(0) P_CLOSE()                                     \
        RD_A(D, 0, 1)                                                    \
        P_OPEN() MFMA16(1) VM(4); P_CLOSE()                              \
        RD_B(D, 1) RD_A(D, 1, 0) STAGE(KT_NEXT, 1, D ^ 1)                \
        P_OPEN() MFMA16(0) P_CLOSE()                                     \
        RD_A(D, 1, 1)                                                    \
        P_OPEN() MFMA16(1) VM(4); P_CLOSE()                              \
    }

#define TILE_LAST(D)                                                     \
    {                                                                    \
        bf16x8 afr[4], bfr[4];                                           \
        RD_B(D, 0) RD_A(D, 0, 0)                                         \
        P_OPEN() MFMA16(0) P_CLOSE()                                     \
        RD_A(D, 0, 1)                                                    \
        P_OPEN() MFMA16(1) VM(0); P_CLOSE()                              \
        RD_B(D, 1) RD_A(D, 1, 0)                                         \
        P_OPEN() MFMA16(0) P_CLOSE()                                     \
        RD_A(D, 1, 1)                                                    \
        P_OPEN() MFMA16(1) P_CLOSE()                                     \
    }

    // ---- prologue: stage tile 0 (both halves) into buf0 ----
    STAGE(0, 0, 0)
    STAGE(0, 1, 0)
    VM(4);                    // S(0,h0) done; S(0,h1) stays in flight
    MEMBAR(); SBAR();

    // ---- tiles 0..13 ----
    for (int kt2 = 0; kt2 < 7; ++kt2) {
        TILE_STEADY(0, 2 * kt2 + 1)
        TILE_STEADY(1, 2 * kt2 + 2)
    }
    // ---- tile 14: stages tile 15 -> buf1 ----
    TILE_STEADY(0, 15)
    // ---- tile 15: compute only (drains at its ph2) ----
    TILE_LAST(1)

    // ------------------- epilogue: tanh + dot(W_v) reduction ----------------
    const int bidx = row0 >> 11;
    float hlv[4], wcv[4], wvv[4];
#pragma unroll
    for (int n = 0; n < 4; ++n) {
        int g = col0 + wcB + n * 16 + lr;
        hlv[n] = hl_plus[bidx * HIDDEN + g];
        wcv[n] = W_cov[g];
        wvv[n] = W_v[g];
    }
#pragma unroll
    for (int am = 0; am < 8; ++am) {
#pragma unroll
        for (int i = 0; i < 4; ++i) {
            int rloc = wrB + am * 16 + kb * 4 + i;
            float cv = cov[row0 + rloc];
            float ep = 0.f;
#pragma unroll
            for (int n = 0; n < 4; ++n) {
                float arg = acc[am][n][i] + hlv[n] + cv * wcv[n];
                ep += tanh_fast(arg) * wvv[n];
            }
            ep += __shfl_xor(ep, 1);
            ep += __shfl_xor(ep, 2);
            ep += __shfl_xor(ep, 4);
            ep += __shfl_xor(ep, 8);
            if (lr == 0) e_buf[rloc][wc] = ep;
        }
    }
    __syncthreads();
    if (tid < 256)
        e_part[(size_t)nt * M_TOT + row0 + tid] =
            e_buf[tid][0] + e_buf[tid][1] + e_buf[tid][2] + e_buf[tid][3];

#undef STAGE
#undef RD_A
#undef RD_B
#undef MFMA16
#undef TILE_STEADY
#undef TILE_LAST
#undef MEMBAR
#undef LGKM0
#undef VM
#undef SBAR
#undef P_OPEN
#undef P_CLOSE
}

// ---------------------------------------------------------------------------
// Kernel 3: per-batch softmax over S=2048; also emits cov_new = cov + a
// ---------------------------------------------------------------------------
__global__ __launch_bounds__(256) void k_softmax(
    const float* __restrict__ e_part, const float* __restrict__ mask,
    const float* __restrict__ cov, const float* __restrict__ b_v,
    float* __restrict__ a_out, float* __restrict__ cov_out)
{
    __shared__ float red[8];
    int b = blockIdx.x, tid = threadIdx.x;
    float bv = b_v[0];
    float ev[8];
    float mx = -1e30f;
#pragma unroll
    for (int j = 0; j < 8; ++j) {
        int s = j * 256 + tid;
        int idx = b * S_SZ + s;
        float e = bv;
#pragma unroll
        for (int p = 0; p < 4; ++p) e += e_part[(size_t)p * M_TOT + idx];
        e += mask[idx] * MASKED_BIAS;
        ev[j] = e;
        mx = fmaxf(mx, e);
    }
#pragma unroll
    for (int off = 32; off; off >>= 1) mx = fmaxf(mx, __shfl_xor(mx, off));
    if ((tid & 63) == 0) red[tid >> 6] = mx;
    __syncthreads();
    mx = fmaxf(fmaxf(red[0], red[1]), fmaxf(red[2], red[3]));
    float sum = 0.f;
#pragma unroll
    for (int j = 0; j < 8; ++j) { ev[j] = __expf(ev[j] - mx); sum += ev[j]; }
#pragma unroll
    for (int off = 32; off; off >>= 1) sum += __shfl_xor(sum, off);
    if ((tid & 63) == 0) red[4 + (tid >> 6)] = sum;
    __syncthreads();
    sum = red[4] + red[5] + red[6] + red[7];
    float inv = 1.f / sum;
#pragma unroll
    for (int j = 0; j < 8; ++j) {
        int idx = b * S_SZ + j * 256 + tid;
        float a = ev[j] * inv;
        a_out[idx]   = a;
        cov_out[idx] = cov[idx] + a;
    }
}

// ---------------------------------------------------------------------------
// Kernel 4: context partials from bf16 K (L3-warm after GEMM), 16 s-chunks
// ---------------------------------------------------------------------------
__global__ __launch_bounds__(256) void k_ctx_part_bf(
    const bf16* __restrict__ Kbf, const float* __restrict__ a_out,
    float* __restrict__ part_out)
{
    int sc = blockIdx.x;   // 0..15
    int b  = blockIdx.y;   // 0..31
    int tid = threadIdx.x;
    const bf16* Kb = Kbf + ((size_t)b * S_SZ + sc * 128) * HIDDEN;
    const float* ab = a_out + b * S_SZ + sc * 128;
    float4 acc = {0.f, 0.f, 0.f, 0.f};
#pragma unroll 4
    for (int s = 0; s < 128; ++s) {
        float av = ab[s];
        bf16x4 kv = *(const bf16x4*)(Kb + (size_t)s * HIDDEN + tid * 4);
        acc.x += av * (float)kv[0];
        acc.y += av * (float)kv[1];
        acc.z += av * (float)kv[2];
        acc.w += av * (float)kv[3];
    }
    ((float4*)part_out)[((size_t)b * 16 + sc) * 256 + tid] = acc;
}

// ---------------------------------------------------------------------------
// Kernel 5: out[b][h] = sum_sc part_out[b][sc][h]
// ---------------------------------------------------------------------------
__global__ __launch_bounds__(256) void k_ctx_reduce(
    const float* __restrict__ part_out, float* __restrict__ out, int nc)
{
    int b = blockIdx.x, tid = threadIdx.x;
    float4 acc = {0.f, 0.f, 0.f, 0.f};
    for (int sc = 0; sc < nc; ++sc) {
        float4 v = ((const float4*)part_out)[((size_t)b * nc + sc) * 256 + tid];
        acc.x += v.x; acc.y += v.y; acc.z += v.z; acc.w += v.w;
    }
    ((float4*)out)[b * 256 + tid] = acc;
}

// ---------------------------------------------------------------------------
extern "C" void kernel_launch(void* const* d_in, const int* in_sizes, int n_in,
                              void* d_out, int out_size, void* d_ws, size_t ws_size,
                              hipStream_t stream)
{
    const float* h     = (const float*)d_in[0];
    const float* Kin   = (const float*)d_in[1];
    const float* cov   = (const float*)d_in[2];
    const float* mask  = (const float*)d_in[3];
    const float* W_h   = (const float*)d_in[4];
    const float* b_h   = (const float*)d_in[5];
    const float* W_K   = (const float*)d_in[6];
    const float* b_K   = (const float*)d_in[7];
    const float* W_cov = (const float*)d_in[8];
    const float* b_cov = (const float*)d_in[9];
    const float* W_v   = (const float*)d_in[10];
    const float* b_v   = (const float*)d_in[11];

    float* out_ctx = (float*)d_out;            // 32*1024
    float* a_out   = out_ctx + B_SZ * HIDDEN;  // 32*2048
    float* cov_out = a_out + M_TOT;            // 32*2048

    float* ws       = (float*)d_ws;
    float* hl_plus  = ws;                        // 32768 f32
    float* e_part   = ws + 32768;                // 4*65536 f32 = 1 MB
    // part_out (2 MB, 32x16x1024 f32) aliases e_part + Bbf region: e_part is
    // dead after k_softmax, Bbf dead after k_fused_g; ctx runs last.
    float* part_out = e_part;
    bf16*  Bbf      = (bf16*)(e_part + 4 * M_TOT);          // 2 MB
    bf16*  Kbf      = (bf16*)((char*)Bbf + (size_t)HIDDEN * HIDDEN * sizeof(bf16));

    k_wconv<<<512, 256, 0, stream>>>(W_K, Bbf);
    k_hlplus<<<8192, 256, 0, stream>>>(h, W_h, b_h, b_K, b_cov, hl_plus);
    k_kconv<<<(M_TOT * HIDDEN / 8) / 256, 256, 0, stream>>>(Kin, Kbf);
    k_fused_g<<<256 * NT_N, 512, 0, stream>>>(
        Kbf, Bbf, hl_plus, W_cov, cov, W_v, e_part);
    k_softmax<<<B_SZ, 256, 0, stream>>>(e_part, mask, cov, b_v, a_out, cov_out);
    dim3 g4(16, B_SZ);
    k_ctx_part_bf<<<g4, 256, 0, stream>>>(Kbf, a_out, part_out);
    k_ctx_reduce<<<B_SZ, 256, 0, stream>>>(part_out, out_ctx, 16);
}

// Round 8
// 301.641 us; speedup vs baseline: 1.2008x; 1.0612x over previous
//
#include <hip/hip_runtime.h>
#include <hip/hip_bf16.h>

#define HIDDEN 1024
#define B_SZ 32
#define S_SZ 2048
#define M_TOT (B_SZ * S_SZ)          // 65536 rows
#define MASKED_BIAS -10000.0f

using bf16   = __bf16;
using bf16x4 = __attribute__((ext_vector_type(4))) __bf16;
using bf16x8 = __attribute__((ext_vector_type(8))) __bf16;
using f32x4  = __attribute__((ext_vector_type(4))) float;

__device__ __forceinline__ float tanh_fast(float x) {
    float xc = fminf(fmaxf(x, -15.f), 15.f);
    float e2 = __expf(2.f * xc);
    return (e2 - 1.f) * __frcp_rn(e2 + 1.f);
}

// ---------------------------------------------------------------------------
// Kernel 0a: W_K f32 -> bf16 (2 MB, L2-resident B operand)
// ---------------------------------------------------------------------------
__global__ __launch_bounds__(256) void k_wconv(
    const float* __restrict__ W, bf16* __restrict__ out)
{
    int i = blockIdx.x * 256 + threadIdx.x;
    const float4* p = (const float4*)W + (size_t)i * 2;
    float4 a = p[0], b = p[1];
    bf16x8 v = { (bf16)a.x, (bf16)a.y, (bf16)a.z, (bf16)a.w,
                 (bf16)b.x, (bf16)b.y, (bf16)b.z, (bf16)b.w };
    *(bf16x8*)(out + (size_t)i * 8) = v;
}

// ---------------------------------------------------------------------------
// Kernel 0b: K f32 -> bf16 (128 MB A operand)
// ---------------------------------------------------------------------------
__global__ __launch_bounds__(256) void k_kconv(
    const float* __restrict__ K, bf16* __restrict__ out)
{
    size_t i = (size_t)blockIdx.x * 256 + threadIdx.x;
    const float4* p = (const float4*)K + i * 2;
    float4 a = p[0], b = p[1];
    bf16x8 v = { (bf16)a.x, (bf16)a.y, (bf16)a.z, (bf16)a.w,
                 (bf16)b.x, (bf16)b.y, (bf16)b.z, (bf16)b.w };
    *(bf16x8*)(out + i * 8) = v;
}

// ---------------------------------------------------------------------------
// Kernel 1: hl_plus[b][g] = dot(h[b,:], W_h[g,:]) + b_h[g] + b_K[g] + b_cov[g]
// ---------------------------------------------------------------------------
__global__ __launch_bounds__(256) void k_hlplus(
    const float* __restrict__ h, const float* __restrict__ W_h,
    const float* __restrict__ b_h, const float* __restrict__ b_K,
    const float* __restrict__ b_cov, float* __restrict__ hl_plus)
{
    int wid  = blockIdx.x * 4 + (threadIdx.x >> 6);
    int lane = threadIdx.x & 63;
    int b = wid & 31;
    int g = wid >> 5;
    const float4* hv = (const float4*)(h + b * HIDDEN);
    const float4* wv = (const float4*)(W_h + g * HIDDEN);
    float acc = 0.f;
#pragma unroll
    for (int i = 0; i < 4; ++i) {
        float4 a = hv[i * 64 + lane];
        float4 w = wv[i * 64 + lane];
        acc += a.x * w.x + a.y * w.y + a.z * w.z + a.w * w.w;
    }
#pragma unroll
    for (int off = 32; off; off >>= 1) acc += __shfl_xor(acc, off);
    if (lane == 0)
        hl_plus[b * HIDDEN + g] = acc + b_h[g] + b_K[g] + b_cov[g];
}

// ===========================================================================
// Kernel 2 (R8): m97-regime fused GEMM+tanh+dot.
// Tile 256x128, BK=32, 512 threads = 8 waves (2M x 4N), per-wave 128x32 out.
// LDS 48KB (2-buf) -> 2 blocks/CU, 16 waves/CU: the other block's MFMA covers
// this block's barrier drain (TLP, m97 mechanism). One __syncthreads per tile.
// All staging via global_load_lds from bf16; 64B-row XOR swizzle (R7-proven
// conflict-free): LDS[row][chunk c] = global chunk c ^ ((row>>1)&3).
// ===========================================================================
#define NT_N 8

__global__ __launch_bounds__(512, 4) void k_fused8(
    const bf16*  __restrict__ Kbf,      // [65536][1024] bf16
    const bf16*  __restrict__ Bbf,      // [1024][1024] bf16 (W_K)
    const float* __restrict__ hl_plus,
    const float* __restrict__ W_cov,
    const float* __restrict__ cov,
    const float* __restrict__ W_v,
    float* __restrict__ e_part)         // [8][65536]
{
    __shared__ __align__(16) bf16 As[2][256][32];   // 32 KB
    __shared__ __align__(16) bf16 Bs[2][128][32];   // 16 KB
    __shared__ float e_buf[256][4];

    const int tid = threadIdx.x;
    const int bid = blockIdx.x;
    // XCD-bijective swizzle: 2048 blocks, 256/XCD, nt fastest within XCD.
    const int lid = (bid & 7) * 256 + (bid >> 3);
    const int mt  = lid >> 3;            // 256 m-tiles (256 rows)
    const int nt  = lid & 7;             // 8 n-tiles (128 cols)
    const int row0 = mt * 256;
    const int col0 = nt * 128;

    const int w    = tid >> 6;           // wave 0..7
    const int lane = tid & 63;
    const int wr   = w >> 2;             // M-half (128 rows)
    const int wc   = w & 3;              // N-quarter (32 cols)
    const int lr   = lane & 15;
    const int kb   = lane >> 4;
    const int colA = (kb ^ ((lr >> 1) & 3)) * 8;   // read-side swizzled col

    // stage geometry: one gload instr per wave = 16 rows x 64B (4x16B chunks);
    // source chunk pre-swizzled: lane l -> chunk (l&3) ^ ((l>>3)&3)
    const int srow = lane >> 2;
    const int gch  = (lane & 3) ^ ((lane >> 3) & 3);
    const bf16* Abase = Kbf + (size_t)(row0 + w * 16 + srow) * HIDDEN + gch * 8;
    const bf16* Bbase = Bbf + (size_t)(col0 + w * 16 + srow) * HIDDEN + gch * 8;

    f32x4 acc[8][2] = {};

    // 3 gloads/thread per K-tile: A rows [0,128)+[128,256), B rows [0,128)
#define STAGE(KT, BUF)                                                    \
    __builtin_amdgcn_global_load_lds(                                     \
        (const __attribute__((address_space(1))) void*)(Abase + (KT) * 32),\
        (__attribute__((address_space(3))) void*)&As[BUF][w * 16][0],     \
        16, 0, 0);                                                        \
    __builtin_amdgcn_global_load_lds(                                     \
        (const __attribute__((address_space(1))) void*)                   \
            (Abase + (size_t)128 * HIDDEN + (KT) * 32),                   \
        (__attribute__((address_space(3))) void*)&As[BUF][128 + w * 16][0],\
        16, 0, 0);                                                        \
    __builtin_amdgcn_global_load_lds(                                     \
        (const __attribute__((address_space(1))) void*)(Bbase + (KT) * 32),\
        (__attribute__((address_space(3))) void*)&Bs[BUF][w * 16][0],     \
        16, 0, 0);

#define TILE_COMPUTE(BUF)                                                 \
    {                                                                     \
        bf16x8 afr[8], bfr[2];                                            \
        _Pragma("unroll") for (int j = 0; j < 8; ++j)                     \
            afr[j] = *(const bf16x8*)                                     \
                &As[BUF][wr * 128 + j * 16 + lr][colA];                   \
        _Pragma("unroll") for (int n = 0; n < 2; ++n)                     \
            bfr[n] = *(const bf16x8*)&Bs[BUF][wc * 32 + n * 16 + lr][colA];\
        __builtin_amdgcn_s_setprio(1);                                    \
        _Pragma("unroll") for (int j = 0; j < 8; ++j)                     \
            _Pragma("unroll") for (int n = 0; n < 2; ++n)                 \
                acc[j][n] = __builtin_amdgcn_mfma_f32_16x16x32_bf16(      \
                    afr[j], bfr[n], acc[j][n], 0, 0, 0);                  \
        __builtin_amdgcn_s_setprio(0);                                    \
    }

    // prologue: stage tile 0 into buf0 (drained by __syncthreads)
    STAGE(0, 0)
    __syncthreads();

    // tiles 0..29 (stage t+1 each; one barrier per tile)
    for (int i = 0; i < 15; ++i) {
        const int t = i * 2;
        STAGE(t + 1, 1)          // tile t   reads buf0, stages t+1 -> buf1
        TILE_COMPUTE(0)
        __syncthreads();
        STAGE(t + 2, 0)          // tile t+1 reads buf1, stages t+2 -> buf0
        TILE_COMPUTE(1)
        __syncthreads();
    }
    // tile 30: stage 31 -> buf1
    STAGE(31, 1)
    TILE_COMPUTE(0)
    __syncthreads();
    // tile 31: compute only
    TILE_COMPUTE(1)

    // ------------------- epilogue: tanh + dot(W_v) reduction ----------------
    const int bidx = row0 >> 11;
    float hlv[2], wcv[2], wvv[2];
#pragma unroll
    for (int n = 0; n < 2; ++n) {
        int g = col0 + wc * 32 + n * 16 + lr;
        hlv[n] = hl_plus[bidx * HIDDEN + g];
        wcv[n] = W_cov[g];
        wvv[n] = W_v[g];
    }
#pragma unroll
    for (int j = 0; j < 8; ++j) {
#pragma unroll
        for (int i = 0; i < 4; ++i) {
            int rloc = wr * 128 + j * 16 + kb * 4 + i;
            float cv = cov[row0 + rloc];
            float ep = 0.f;
#pragma unroll
            for (int n = 0; n < 2; ++n) {
                float arg = acc[j][n][i] + hlv[n] + cv * wcv[n];
                ep += tanh_fast(arg) * wvv[n];
            }
            ep += __shfl_xor(ep, 1);
            ep += __shfl_xor(ep, 2);
            ep += __shfl_xor(ep, 4);
            ep += __shfl_xor(ep, 8);
            if (lr == 0) e_buf[rloc][wc] = ep;
        }
    }
    __syncthreads();
    if (tid < 256)
        e_part[(size_t)nt * M_TOT + row0 + tid] =
            e_buf[tid][0] + e_buf[tid][1] + e_buf[tid][2] + e_buf[tid][3];

#undef STAGE
#undef TILE_COMPUTE
}

// ---------------------------------------------------------------------------
// Kernel 3: per-batch softmax over S=2048; also emits cov_new = cov + a
// ---------------------------------------------------------------------------
__global__ __launch_bounds__(256) void k_softmax(
    const float* __restrict__ e_part, const float* __restrict__ mask,
    const float* __restrict__ cov, const float* __restrict__ b_v,
    float* __restrict__ a_out, float* __restrict__ cov_out)
{
    __shared__ float red[8];
    int b = blockIdx.x, tid = threadIdx.x;
    float bv = b_v[0];
    float ev[8];
    float mx = -1e30f;
#pragma unroll
    for (int j = 0; j < 8; ++j) {
        int s = j * 256 + tid;
        int idx = b * S_SZ + s;
        float e = bv;
#pragma unroll
        for (int p = 0; p < 8; ++p) e += e_part[(size_t)p * M_TOT + idx];
        e += mask[idx] * MASKED_BIAS;
        ev[j] = e;
        mx = fmaxf(mx, e);
    }
#pragma unroll
    for (int off = 32; off; off >>= 1) mx = fmaxf(mx, __shfl_xor(mx, off));
    if ((tid & 63) == 0) red[tid >> 6] = mx;
    __syncthreads();
    mx = fmaxf(fmaxf(red[0], red[1]), fmaxf(red[2], red[3]));
    float sum = 0.f;
#pragma unroll
    for (int j = 0; j < 8; ++j) { ev[j] = __expf(ev[j] - mx); sum += ev[j]; }
#pragma unroll
    for (int off = 32; off; off >>= 1) sum += __shfl_xor(sum, off);
    if ((tid & 63) == 0) red[4 + (tid >> 6)] = sum;
    __syncthreads();
    sum = red[4] + red[5] + red[6] + red[7];
    float inv = 1.f / sum;
#pragma unroll
    for (int j = 0; j < 8; ++j) {
        int idx = b * S_SZ + j * 256 + tid;
        float a = ev[j] * inv;
        a_out[idx]   = a;
        cov_out[idx] = cov[idx] + a;
    }
}

// ---------------------------------------------------------------------------
// Kernel 4: context partials from bf16 K (L3-warm after GEMM), 16 s-chunks
// ---------------------------------------------------------------------------
__global__ __launch_bounds__(256) void k_ctx_part_bf(
    const bf16* __restrict__ Kbf, const float* __restrict__ a_out,
    float* __restrict__ part_out)
{
    int sc = blockIdx.x;   // 0..15
    int b  = blockIdx.y;   // 0..31
    int tid = threadIdx.x;
    const bf16* Kb = Kbf + ((size_t)b * S_SZ + sc * 128) * HIDDEN;
    const float* ab = a_out + b * S_SZ + sc * 128;
    float4 acc = {0.f, 0.f, 0.f, 0.f};
#pragma unroll 4
    for (int s = 0; s < 128; ++s) {
        float av = ab[s];
        bf16x4 kv = *(const bf16x4*)(Kb + (size_t)s * HIDDEN + tid * 4);
        acc.x += av * (float)kv[0];
        acc.y += av * (float)kv[1];
        acc.z += av * (float)kv[2];
        acc.w += av * (float)kv[3];
    }
    ((float4*)part_out)[((size_t)b * 16 + sc) * 256 + tid] = acc;
}

// ---------------------------------------------------------------------------
// Kernel 5: out[b][h] = sum_sc part_out[b][sc][h]
// ---------------------------------------------------------------------------
__global__ __launch_bounds__(256) void k_ctx_reduce(
    const float* __restrict__ part_out, float* __restrict__ out, int nc)
{
    int b = blockIdx.x, tid = threadIdx.x;
    float4 acc = {0.f, 0.f, 0.f, 0.f};
    for (int sc = 0; sc < nc; ++sc) {
        float4 v = ((const float4*)part_out)[((size_t)b * nc + sc) * 256 + tid];
        acc.x += v.x; acc.y += v.y; acc.z += v.z; acc.w += v.w;
    }
    ((float4*)out)[b * 256 + tid] = acc;
}

// ---------------------------------------------------------------------------
extern "C" void kernel_launch(void* const* d_in, const int* in_sizes, int n_in,
                              void* d_out, int out_size, void* d_ws, size_t ws_size,
                              hipStream_t stream)
{
    const float* h     = (const float*)d_in[0];
    const float* Kin   = (const float*)d_in[1];
    const float* cov   = (const float*)d_in[2];
    const float* mask  = (const float*)d_in[3];
    const float* W_h   = (const float*)d_in[4];
    const float* b_h   = (const float*)d_in[5];
    const float* W_K   = (const float*)d_in[6];
    const float* b_K   = (const float*)d_in[7];
    const float* W_cov = (const float*)d_in[8];
    const float* b_cov = (const float*)d_in[9];
    const float* W_v   = (const float*)d_in[10];
    const float* b_v   = (const float*)d_in[11];

    float* out_ctx = (float*)d_out;            // 32*1024
    float* a_out   = out_ctx + B_SZ * HIDDEN;  // 32*2048
    float* cov_out = a_out + M_TOT;            // 32*2048

    float* ws       = (float*)d_ws;
    float* hl_plus  = ws;                        // 32768 f32
    float* e_part   = ws + 32768;                // 8*65536 f32 = 2 MB
    float* part_out = e_part;                    // alias (sequential use, 2 MB)
    bf16*  Bbf      = (bf16*)(e_part + 8 * M_TOT);          // 2 MB
    bf16*  Kbf      = (bf16*)((char*)Bbf + (size_t)HIDDEN * HIDDEN * sizeof(bf16));

    k_wconv<<<512, 256, 0, stream>>>(W_K, Bbf);
    k_hlplus<<<8192, 256, 0, stream>>>(h, W_h, b_h, b_K, b_cov, hl_plus);
    k_kconv<<<(M_TOT * HIDDEN / 8) / 256, 256, 0, stream>>>(Kin, Kbf);
    k_fused8<<<256 * NT_N, 512, 0, stream>>>(
        Kbf, Bbf, hl_plus, W_cov, cov, W_v, e_part);
    k_softmax<<<B_SZ, 256, 0, stream>>>(e_part, mask, cov, b_v, a_out, cov_out);
    dim3 g4(16, B_SZ);
    k_ctx_part_bf<<<g4, 256, 0, stream>>>(Kbf, a_out, part_out);
    k_ctx_reduce<<<B_SZ, 256, 0, stream>>>(part_out, out_ctx, 16);
}

// Round 9
// 286.233 us; speedup vs baseline: 1.2654x; 1.0538x over previous
//
#include <hip/hip_runtime.h>
#include <hip/hip_bf16.h>

#define HIDDEN 1024
#define B_SZ 32
#define S_SZ 2048
#define M_TOT (B_SZ * S_SZ)          // 65536 rows
#define MASKED_BIAS -10000.0f

using bf16   = __bf16;
using bf16x4 = __attribute__((ext_vector_type(4))) __bf16;
using bf16x8 = __attribute__((ext_vector_type(8))) __bf16;
using f32x4  = __attribute__((ext_vector_type(4))) float;

__device__ __forceinline__ float tanh_fast(float x) {
    float xc = fminf(fmaxf(x, -15.f), 15.f);
    float e2 = __expf(2.f * xc);
    return (e2 - 1.f) * __frcp_rn(e2 + 1.f);
}

// ---------------------------------------------------------------------------
// Kernel 0a: W_K f32 -> bf16 (2 MB, L2-resident B operand)
// ---------------------------------------------------------------------------
__global__ __launch_bounds__(256) void k_wconv(
    const float* __restrict__ W, bf16* __restrict__ out)
{
    int i = blockIdx.x * 256 + threadIdx.x;
    const float4* p = (const float4*)W + (size_t)i * 2;
    float4 a = p[0], b = p[1];
    bf16x8 v = { (bf16)a.x, (bf16)a.y, (bf16)a.z, (bf16)a.w,
                 (bf16)b.x, (bf16)b.y, (bf16)b.z, (bf16)b.w };
    *(bf16x8*)(out + (size_t)i * 8) = v;
}

// ---------------------------------------------------------------------------
// Kernel 0b: K f32 -> bf16 (128 MB A operand)
// ---------------------------------------------------------------------------
__global__ __launch_bounds__(256) void k_kconv(
    const float* __restrict__ K, bf16* __restrict__ out)
{
    size_t i = (size_t)blockIdx.x * 256 + threadIdx.x;
    const float4* p = (const float4*)K + i * 2;
    float4 a = p[0], b = p[1];
    bf16x8 v = { (bf16)a.x, (bf16)a.y, (bf16)a.z, (bf16)a.w,
                 (bf16)b.x, (bf16)b.y, (bf16)b.z, (bf16)b.w };
    *(bf16x8*)(out + i * 8) = v;
}

// ---------------------------------------------------------------------------
// Kernel 1: hl_plus[b][g] = dot(h[b,:], W_h[g,:]) + b_h[g] + b_K[g] + b_cov[g]
// ---------------------------------------------------------------------------
__global__ __launch_bounds__(256) void k_hlplus(
    const float* __restrict__ h, const float* __restrict__ W_h,
    const float* __restrict__ b_h, const float* __restrict__ b_K,
    const float* __restrict__ b_cov, float* __restrict__ hl_plus)
{
    int wid  = blockIdx.x * 4 + (threadIdx.x >> 6);
    int lane = threadIdx.x & 63;
    int b = wid & 31;
    int g = wid >> 5;
    const float4* hv = (const float4*)(h + b * HIDDEN);
    const float4* wv = (const float4*)(W_h + g * HIDDEN);
    float acc = 0.f;
#pragma unroll
    for (int i = 0; i < 4; ++i) {
        float4 a = hv[i * 64 + lane];
        float4 w = wv[i * 64 + lane];
        acc += a.x * w.x + a.y * w.y + a.z * w.z + a.w * w.w;
    }
#pragma unroll
    for (int off = 32; off; off >>= 1) acc += __shfl_xor(acc, off);
    if (lane == 0)
        hl_plus[b * HIDDEN + g] = acc + b_h[g] + b_K[g] + b_cov[g];
}

// ===========================================================================
// Kernel 2 (R9): R8 skeleton with m97 wave economics.
// Tile 256x128, BK=32, 512 threads = 8 waves as 4M x 2N -> wave tile 64x64
// (4x4 fragments): 8 ds_read_b128 per 16 MFMA = 32 FLOP per LDS byte (vs
// R8's 25.6) -> LDS-BW no longer the binding constraint.
// 2 blocks/CU (48KB LDS + e_buf), one __syncthreads per K-tile, all staging
// via global_load_lds from bf16 with the R7-proven conflict-free XOR swizzle:
// LDS[row][chunk c] = global chunk c ^ ((row>>1)&3).
// ===========================================================================
#define NT_N 8

__global__ __launch_bounds__(512, 4) void k_fused9(
    const bf16*  __restrict__ Kbf,      // [65536][1024] bf16
    const bf16*  __restrict__ Bbf,      // [1024][1024] bf16 (W_K)
    const float* __restrict__ hl_plus,
    const float* __restrict__ W_cov,
    const float* __restrict__ cov,
    const float* __restrict__ W_v,
    float* __restrict__ e_part)         // [8][65536]
{
    __shared__ __align__(16) bf16 As[2][256][32];   // 32 KB
    __shared__ __align__(16) bf16 Bs[2][128][32];   // 16 KB
    __shared__ float e_buf[256][2];

    const int tid = threadIdx.x;
    const int bid = blockIdx.x;
    // XCD-bijective swizzle: 2048 blocks, 256/XCD, nt fastest within XCD.
    const int lid = (bid & 7) * 256 + (bid >> 3);
    const int mt  = lid >> 3;            // 256 m-tiles (256 rows)
    const int nt  = lid & 7;             // 8 n-tiles (128 cols)
    const int row0 = mt * 256;
    const int col0 = nt * 128;

    const int w    = tid >> 6;           // wave 0..7
    const int lane = tid & 63;
    const int wm   = w >> 1;             // M-quarter (64 rows)
    const int wn   = w & 1;              // N-half    (64 cols)
    const int lr   = lane & 15;
    const int kb   = lane >> 4;
    const int colA = (kb ^ ((lr >> 1) & 3)) * 8;   // read-side swizzled col

    // stage geometry: one gload instr per wave = 16 rows x 64B (4x16B chunks);
    // source chunk pre-swizzled: lane l -> chunk (l&3) ^ ((l>>3)&3)
    const int srow = lane >> 2;
    const int gch  = (lane & 3) ^ ((lane >> 3) & 3);
    const bf16* Abase = Kbf + (size_t)(row0 + w * 16 + srow) * HIDDEN + gch * 8;
    const bf16* Bbase = Bbf + (size_t)(col0 + w * 16 + srow) * HIDDEN + gch * 8;

    f32x4 acc[4][4] = {};

    // 3 gloads/thread per K-tile: A rows [0,128)+[128,256), B rows [0,128)
#define STAGE(KT, BUF)                                                    \
    __builtin_amdgcn_global_load_lds(                                     \
        (const __attribute__((address_space(1))) void*)(Abase + (KT) * 32),\
        (__attribute__((address_space(3))) void*)&As[BUF][w * 16][0],     \
        16, 0, 0);                                                        \
    __builtin_amdgcn_global_load_lds(                                     \
        (const __attribute__((address_space(1))) void*)                   \
            (Abase + (size_t)128 * HIDDEN + (KT) * 32),                   \
        (__attribute__((address_space(3))) void*)&As[BUF][128 + w * 16][0],\
        16, 0, 0);                                                        \
    __builtin_amdgcn_global_load_lds(                                     \
        (const __attribute__((address_space(1))) void*)(Bbase + (KT) * 32),\
        (__attribute__((address_space(3))) void*)&Bs[BUF][w * 16][0],     \
        16, 0, 0);

#define TILE_COMPUTE(BUF)                                                 \
    {                                                                     \
        bf16x8 afr[4], bfr[4];                                            \
        _Pragma("unroll") for (int j = 0; j < 4; ++j)                     \
            afr[j] = *(const bf16x8*)                                     \
                &As[BUF][wm * 64 + j * 16 + lr][colA];                    \
        _Pragma("unroll") for (int n = 0; n < 4; ++n)                     \
            bfr[n] = *(const bf16x8*)&Bs[BUF][wn * 64 + n * 16 + lr][colA];\
        __builtin_amdgcn_s_setprio(1);                                    \
        _Pragma("unroll") for (int j = 0; j < 4; ++j)                     \
            _Pragma("unroll") for (int n = 0; n < 4; ++n)                 \
                acc[j][n] = __builtin_amdgcn_mfma_f32_16x16x32_bf16(      \
                    afr[j], bfr[n], acc[j][n], 0, 0, 0);                  \
        __builtin_amdgcn_s_setprio(0);                                    \
    }

    // prologue: stage tile 0 into buf0 (drained by __syncthreads)
    STAGE(0, 0)
    __syncthreads();

    // tiles 0..29 (stage t+1 each; one barrier per tile)
    for (int i = 0; i < 15; ++i) {
        const int t = i * 2;
        STAGE(t + 1, 1)          // tile t   reads buf0, stages t+1 -> buf1
        TILE_COMPUTE(0)
        __syncthreads();
        STAGE(t + 2, 0)          // tile t+1 reads buf1, stages t+2 -> buf0
        TILE_COMPUTE(1)
        __syncthreads();
    }
    // tile 30: stage 31 -> buf1
    STAGE(31, 1)
    TILE_COMPUTE(0)
    __syncthreads();
    // tile 31: compute only
    TILE_COMPUTE(1)

    // ------------------- epilogue: tanh + dot(W_v) reduction ----------------
    const int bidx = row0 >> 11;
    float hlv[4], wcv[4], wvv[4];
#pragma unroll
    for (int n = 0; n < 4; ++n) {
        int g = col0 + wn * 64 + n * 16 + lr;
        hlv[n] = hl_plus[bidx * HIDDEN + g];
        wcv[n] = W_cov[g];
        wvv[n] = W_v[g];
    }
#pragma unroll
    for (int j = 0; j < 4; ++j) {
#pragma unroll
        for (int i = 0; i < 4; ++i) {
            int rloc = wm * 64 + j * 16 + kb * 4 + i;
            float cv = cov[row0 + rloc];
            float ep = 0.f;
#pragma unroll
            for (int n = 0; n < 4; ++n) {
                float arg = acc[j][n][i] + hlv[n] + cv * wcv[n];
                ep += tanh_fast(arg) * wvv[n];
            }
            ep += __shfl_xor(ep, 1);
            ep += __shfl_xor(ep, 2);
            ep += __shfl_xor(ep, 4);
            ep += __shfl_xor(ep, 8);
            if (lr == 0) e_buf[rloc][wn] = ep;
        }
    }
    __syncthreads();
    if (tid < 256)
        e_part[(size_t)nt * M_TOT + row0 + tid] = e_buf[tid][0] + e_buf[tid][1];

#undef STAGE
#undef TILE_COMPUTE
}

// ---------------------------------------------------------------------------
// Kernel 3: per-batch softmax over S=2048; also emits cov_new = cov + a
// ---------------------------------------------------------------------------
__global__ __launch_bounds__(256) void k_softmax(
    const float* __restrict__ e_part, const float* __restrict__ mask,
    const float* __restrict__ cov, const float* __restrict__ b_v,
    float* __restrict__ a_out, float* __restrict__ cov_out)
{
    __shared__ float red[8];
    int b = blockIdx.x, tid = threadIdx.x;
    float bv = b_v[0];
    float ev[8];
    float mx = -1e30f;
#pragma unroll
    for (int j = 0; j < 8; ++j) {
        int s = j * 256 + tid;
        int idx = b * S_SZ + s;
        float e = bv;
#pragma unroll
        for (int p = 0; p < 8; ++p) e += e_part[(size_t)p * M_TOT + idx];
        e += mask[idx] * MASKED_BIAS;
        ev[j] = e;
        mx = fmaxf(mx, e);
    }
#pragma unroll
    for (int off = 32; off; off >>= 1) mx = fmaxf(mx, __shfl_xor(mx, off));
    if ((tid & 63) == 0) red[tid >> 6] = mx;
    __syncthreads();
    mx = fmaxf(fmaxf(red[0], red[1]), fmaxf(red[2], red[3]));
    float sum = 0.f;
#pragma unroll
    for (int j = 0; j < 8; ++j) { ev[j] = __expf(ev[j] - mx); sum += ev[j]; }
#pragma unroll
    for (int off = 32; off; off >>= 1) sum += __shfl_xor(sum, off);
    if ((tid & 63) == 0) red[4 + (tid >> 6)] = sum;
    __syncthreads();
    sum = red[4] + red[5] + red[6] + red[7];
    float inv = 1.f / sum;
#pragma unroll
    for (int j = 0; j < 8; ++j) {
        int idx = b * S_SZ + j * 256 + tid;
        float a = ev[j] * inv;
        a_out[idx]   = a;
        cov_out[idx] = cov[idx] + a;
    }
}

// ---------------------------------------------------------------------------
// Kernel 4: context partials from bf16 K (L3-warm after GEMM), 16 s-chunks
// ---------------------------------------------------------------------------
__global__ __launch_bounds__(256) void k_ctx_part_bf(
    const bf16* __restrict__ Kbf, const float* __restrict__ a_out,
    float* __restrict__ part_out)
{
    int sc = blockIdx.x;   // 0..15
    int b  = blockIdx.y;   // 0..31
    int tid = threadIdx.x;
    const bf16* Kb = Kbf + ((size_t)b * S_SZ + sc * 128) * HIDDEN;
    const float* ab = a_out + b * S_SZ + sc * 128;
    float4 acc = {0.f, 0.f, 0.f, 0.f};
#pragma unroll 4
    for (int s = 0; s < 128; ++s) {
        float av = ab[s];
        bf16x4 kv = *(const bf16x4*)(Kb + (size_t)s * HIDDEN + tid * 4);
        acc.x += av * (float)kv[0];
        acc.y += av * (float)kv[1];
        acc.z += av * (float)kv[2];
        acc.w += av * (float)kv[3];
    }
    ((float4*)part_out)[((size_t)b * 16 + sc) * 256 + tid] = acc;
}

// ---------------------------------------------------------------------------
// Kernel 5: out[b][h] = sum_sc part_out[b][sc][h]
// ---------------------------------------------------------------------------
__global__ __launch_bounds__(256) void k_ctx_reduce(
    const float* __restrict__ part_out, float* __restrict__ out, int nc)
{
    int b = blockIdx.x, tid = threadIdx.x;
    float4 acc = {0.f, 0.f, 0.f, 0.f};
    for (int sc = 0; sc < nc; ++sc) {
        float4 v = ((const float4*)part_out)[((size_t)b * nc + sc) * 256 + tid];
        acc.x += v.x; acc.y += v.y; acc.z += v.z; acc.w += v.w;
    }
    ((float4*)out)[b * 256 + tid] = acc;
}

// ---------------------------------------------------------------------------
extern "C" void kernel_launch(void* const* d_in, const int* in_sizes, int n_in,
                              void* d_out, int out_size, void* d_ws, size_t ws_size,
                              hipStream_t stream)
{
    const float* h     = (const float*)d_in[0];
    const float* Kin   = (const float*)d_in[1];
    const float* cov   = (const float*)d_in[2];
    const float* mask  = (const float*)d_in[3];
    const float* W_h   = (const float*)d_in[4];
    const float* b_h   = (const float*)d_in[5];
    const float* W_K   = (const float*)d_in[6];
    const float* b_K   = (const float*)d_in[7];
    const float* W_cov = (const float*)d_in[8];
    const float* b_cov = (const float*)d_in[9];
    const float* W_v   = (const float*)d_in[10];
    const float* b_v   = (const float*)d_in[11];

    float* out_ctx = (float*)d_out;            // 32*1024
    float* a_out   = out_ctx + B_SZ * HIDDEN;  // 32*2048
    float* cov_out = a_out + M_TOT;            // 32*2048

    float* ws       = (float*)d_ws;
    float* hl_plus  = ws;                        // 32768 f32
    float* e_part   = ws + 32768;                // 8*65536 f32 = 2 MB
    float* part_out = e_part;                    // alias (sequential use, 2 MB)
    bf16*  Bbf      = (bf16*)(e_part + 8 * M_TOT);          // 2 MB
    bf16*  Kbf      = (bf16*)((char*)Bbf + (size_t)HIDDEN * HIDDEN * sizeof(bf16));

    k_wconv<<<512, 256, 0, stream>>>(W_K, Bbf);
    k_hlplus<<<8192, 256, 0, stream>>>(h, W_h, b_h, b_K, b_cov, hl_plus);
    k_kconv<<<(M_TOT * HIDDEN / 8) / 256, 256, 0, stream>>>(Kin, Kbf);
    k_fused9<<<256 * NT_N, 512, 0, stream>>>(
        Kbf, Bbf, hl_plus, W_cov, cov, W_v, e_part);
    k_softmax<<<B_SZ, 256, 0, stream>>>(e_part, mask, cov, b_v, a_out, cov_out);
    dim3 g4(16, B_SZ);
    k_ctx_part_bf<<<g4, 256, 0, stream>>>(Kbf, a_out, part_out);
    k_ctx_reduce<<<B_SZ, 256, 0, stream>>>(part_out, out_ctx, 16);
}